// Round 1
// 1323.298 us; speedup vs baseline: 1.1680x; 1.1680x over previous
//
#include <hip/hip_runtime.h>

#define N_POI 100000
#define N_EDGE 50000
#define NNZ 3200000
#define D 128

// CSR build tiling: NNZ split into C_CH chunks; bin space sharded BPS bins/shard.
// p2e: 4 shards * 12500 = 50000 bins; e2p: 8 shards * 12500 = 100000 bins.
// 12500 ints = 50KB LDS -> 3 blocks/CU.
#define C_CH 64
#define BPS 12500

__device__ inline unsigned short f2bf(float f) {  // RN-even fp32->bf16
    unsigned int u = __float_as_uint(f);
    return (unsigned short)((u + 0x7fff + ((u >> 16) & 1)) >> 16);
}
__device__ inline float bf2f(unsigned short u) {
    return __uint_as_float(((unsigned int)u) << 16);
}
__device__ inline int2 nt_int2(const int2* p) {
    unsigned long long u = __builtin_nontemporal_load((const unsigned long long*)p);
    int2 r; r.x = (int)(unsigned)(u & 0xffffffffull); r.y = (int)(unsigned)(u >> 32);
    return r;
}

// dst1 = dst2 = src (float4 grid-stride)
__global__ __launch_bounds__(256) void copy2_kernel(const float* __restrict__ src,
                                                    float* __restrict__ dst1,
                                                    float* __restrict__ dst2, int n4) {
    int i = blockIdx.x * 256 + threadIdx.x;
    int stride = gridDim.x * 256;
    const float4* s = (const float4*)src;
    float4* d1 = (float4*)dst1;
    float4* d2 = (float4*)dst2;
    for (; i < n4; i += stride) {
        float4 v = s[i];
        d1[i] = v;
        d2[i] = v;
    }
}

// WdT[j][i] = (Wf1 @ Wpoi)[i][j],  WcT[j][i] = (Wf2 @ Wedge)[i][j]
__global__ __launch_bounds__(128) void wcombo_kernel(const float* __restrict__ Wpoi,
                                                     const float* __restrict__ Wedge,
                                                     const float* __restrict__ Wfus,
                                                     float* __restrict__ WdT,
                                                     float* __restrict__ WcT) {
    int i = blockIdx.x;
    int j = threadIdx.x;
    float s1 = 0.f, s2 = 0.f;
    for (int k = 0; k < D; ++k) {
        float f1 = Wfus[i * 256 + k];
        float f2 = Wfus[i * 256 + 128 + k];
        s1 += f1 * Wpoi[k * D + j];
        s2 += f2 * Wedge[k * D + j];
    }
    WdT[j * D + i] = s1;
    WcT[j * D + i] = s2;
}

// Y[r][c] = sum_k X[r][k] * MT[k][c].  BF16OUT: Y is bf16 (ushort), else fp32.
template <bool BF16OUT>
__global__ __launch_bounds__(256) void dense_xmT(const float* __restrict__ X,
                                                 const float* __restrict__ MT,
                                                 void* __restrict__ Yv, int nrows) {
    __shared__ float mt[D * D];
    __shared__ float xs[32 * D];
    for (int i = threadIdx.x; i < D * D / 4; i += 256)
        ((float4*)mt)[i] = ((const float4*)MT)[i];

    int ntiles = (nrows + 31) >> 5;
    int rg = threadIdx.x >> 5;
    int cg = threadIdx.x & 31;
    int r0 = rg * 4;
    int c0 = cg * 4;

    for (int tile = blockIdx.x; tile < ntiles; tile += gridDim.x) {
        int rbase = tile * 32;
        int nr = min(32, nrows - rbase);
        __syncthreads();
        for (int i = threadIdx.x; i < nr * 32; i += 256)
            ((float4*)xs)[i] = ((const float4*)(X + (size_t)rbase * D))[i];
        __syncthreads();

        float4 a0 = {0, 0, 0, 0}, a1 = {0, 0, 0, 0}, a2 = {0, 0, 0, 0}, a3 = {0, 0, 0, 0};
#pragma unroll 4
        for (int k = 0; k < D; ++k) {
            float4 m = *(const float4*)&mt[k * D + c0];
            float x0 = xs[(r0 + 0) * D + k];
            float x1 = xs[(r0 + 1) * D + k];
            float x2 = xs[(r0 + 2) * D + k];
            float x3 = xs[(r0 + 3) * D + k];
            a0.x += x0 * m.x; a0.y += x0 * m.y; a0.z += x0 * m.z; a0.w += x0 * m.w;
            a1.x += x1 * m.x; a1.y += x1 * m.y; a1.z += x1 * m.z; a1.w += x1 * m.w;
            a2.x += x2 * m.x; a2.y += x2 * m.y; a2.z += x2 * m.z; a2.w += x2 * m.w;
            a3.x += x3 * m.x; a3.y += x3 * m.y; a3.z += x3 * m.z; a3.w += x3 * m.w;
        }
        float4 accs[4] = {a0, a1, a2, a3};
#pragma unroll
        for (int t = 0; t < 4; ++t) {
            if (r0 + t < nr) {
                size_t off = (size_t)(rbase + r0 + t) * D + c0;
                if (BF16OUT) {
                    ushort4 u;
                    u.x = f2bf(accs[t].x); u.y = f2bf(accs[t].y);
                    u.z = f2bf(accs[t].z); u.w = f2bf(accs[t].w);
                    *(ushort4*)&((unsigned short*)Yv)[off] = u;
                } else {
                    *(float4*)&((float*)Yv)[off] = accs[t];
                }
            }
        }
    }
}

// ---- atomic-free CSR build ----
// Kernel A: block (shard, chunk) LDS-histograms its chunk; writes partial[c][bin]
// (coalesced). No global atomics.
__global__ __launch_bounds__(256) void hist_shard(const int* __restrict__ r,
                                                  int* __restrict__ partial,
                                                  int logS, int nb) {
    extern __shared__ int h[];
    int shard = blockIdx.x & ((1 << logS) - 1);
    int c = blockIdx.x >> logS;
    int lo = shard * BPS;
    for (int i = threadIdx.x; i < BPS; i += 256) h[i] = 0;
    __syncthreads();
    const int chunk4 = (NNZ / C_CH) >> 2;  // 12500 int4 per chunk
    const int4* r4 = (const int4*)r + (size_t)c * chunk4;
    for (int k = threadIdx.x; k < chunk4; k += 256) {
        int4 rr = r4[k];
        unsigned b0 = (unsigned)(rr.x - lo);
        unsigned b1 = (unsigned)(rr.y - lo);
        unsigned b2 = (unsigned)(rr.z - lo);
        unsigned b3 = (unsigned)(rr.w - lo);
        if (b0 < (unsigned)BPS) atomicAdd(&h[b0], 1);
        if (b1 < (unsigned)BPS) atomicAdd(&h[b1], 1);
        if (b2 < (unsigned)BPS) atomicAdd(&h[b2], 1);
        if (b3 < (unsigned)BPS) atomicAdd(&h[b3], 1);
    }
    __syncthreads();
    int* dst = partial + (size_t)c * nb + lo;
    for (int i = threadIdx.x; i < BPS; i += 256) dst[i] = h[i];
}

// Kernel B: counts[bin] = sum_c partial[c][bin] (feeds the existing scan).
__global__ __launch_bounds__(256) void reduce_partials(const int* __restrict__ partial,
                                                       int* __restrict__ counts, int nb) {
    int bin = blockIdx.x * 256 + threadIdx.x;
    if (bin >= nb) return;
    int s = 0;
#pragma unroll 8
    for (int c = 0; c < C_CH; ++c) s += partial[(size_t)c * nb + bin];
    counts[bin] = s;
}

// Kernel C: in-place exclusive prefix over chunks: partial[c][bin] becomes the
// absolute cv offset where chunk c's entries for bin start.
__global__ __launch_bounds__(256) void prefix_chunks(int* __restrict__ partial,
                                                     const int* __restrict__ rp, int nb) {
    int bin = blockIdx.x * 256 + threadIdx.x;
    if (bin >= nb) return;
    int run = rp[bin];
    for (int c = 0; c < C_CH; ++c) {
        size_t idx = (size_t)c * nb + bin;
        int v = partial[idx];
        partial[idx] = run;
        run += v;
    }
}

// Kernel D: block (shard, chunk) loads its offset column into LDS cursors and
// scatters (col,val) with LDS atomics only. Disjoint output ranges by
// construction -> no global atomics.
__global__ __launch_bounds__(256) void scatter_lds(const int* __restrict__ r,
                                                   const int* __restrict__ cidx,
                                                   const float* __restrict__ val,
                                                   const int* __restrict__ offs,
                                                   int2* __restrict__ cv,
                                                   int logS, int nb) {
    extern __shared__ int cur[];
    int shard = blockIdx.x & ((1 << logS) - 1);
    int c = blockIdx.x >> logS;
    int lo = shard * BPS;
    const int* src = offs + (size_t)c * nb + lo;
    for (int i = threadIdx.x; i < BPS; i += 256) cur[i] = src[i];
    __syncthreads();
    const int chunk4 = (NNZ / C_CH) >> 2;
    size_t base4 = (size_t)c * chunk4;
    const int4* r4 = (const int4*)r + base4;
    const int4* c4 = (const int4*)cidx + base4;
    const float4* v4 = (const float4*)val + base4;
    for (int k = threadIdx.x; k < chunk4; k += 256) {
        int4 rr = r4[k];
        int4 cc = c4[k];
        float4 vv = v4[k];
        unsigned b0 = (unsigned)(rr.x - lo);
        if (b0 < (unsigned)BPS) { int p = atomicAdd(&cur[b0], 1); cv[p] = make_int2(cc.x, __float_as_int(vv.x)); }
        unsigned b1 = (unsigned)(rr.y - lo);
        if (b1 < (unsigned)BPS) { int p = atomicAdd(&cur[b1], 1); cv[p] = make_int2(cc.y, __float_as_int(vv.y)); }
        unsigned b2 = (unsigned)(rr.z - lo);
        if (b2 < (unsigned)BPS) { int p = atomicAdd(&cur[b2], 1); cv[p] = make_int2(cc.z, __float_as_int(vv.z)); }
        unsigned b3 = (unsigned)(rr.w - lo);
        if (b3 < (unsigned)BPS) { int p = atomicAdd(&cur[b3], 1); cv[p] = make_int2(cc.w, __float_as_int(vv.w)); }
    }
}

// ---- 3-phase multi-block exclusive scan (1024 elems/block) ----
__global__ __launch_bounds__(256) void scan_partials(const int* __restrict__ counts, int n,
                                                     int* __restrict__ partials) {
    __shared__ int red[256];
    int i0 = blockIdx.x * 1024 + threadIdx.x * 4;
    int s = 0;
#pragma unroll
    for (int t = 0; t < 4; ++t)
        if (i0 + t < n) s += counts[i0 + t];
    red[threadIdx.x] = s;
    __syncthreads();
    for (int off = 128; off > 0; off >>= 1) {
        if (threadIdx.x < off) red[threadIdx.x] += red[threadIdx.x + off];
        __syncthreads();
    }
    if (threadIdx.x == 0) partials[blockIdx.x] = red[0];
}

__global__ __launch_bounds__(128) void scan_top(int* partials, int nb) {
    __shared__ int buf[128];
    int v = (threadIdx.x < nb) ? partials[threadIdx.x] : 0;
    buf[threadIdx.x] = v;
    __syncthreads();
    for (int off = 1; off < 128; off <<= 1) {
        int t = (threadIdx.x >= off) ? buf[threadIdx.x - off] : 0;
        __syncthreads();
        buf[threadIdx.x] += t;
        __syncthreads();
    }
    if (threadIdx.x < nb) partials[threadIdx.x] = buf[threadIdx.x] - v;
}

__global__ __launch_bounds__(256) void scan_apply(const int* __restrict__ counts, int n,
                                                  const int* __restrict__ partials,
                                                  int* __restrict__ rp, int* __restrict__ next,
                                                  int total) {
    __shared__ int buf[256];
    int i0 = blockIdx.x * 1024 + threadIdx.x * 4;
    int v[4];
#pragma unroll
    for (int t = 0; t < 4; ++t) v[t] = (i0 + t < n) ? counts[i0 + t] : 0;
    int s = v[0] + v[1] + v[2] + v[3];
    buf[threadIdx.x] = s;
    __syncthreads();
    for (int off = 1; off < 256; off <<= 1) {
        int t = (threadIdx.x >= off) ? buf[threadIdx.x - off] : 0;
        __syncthreads();
        buf[threadIdx.x] += t;
        __syncthreads();
    }
    int excl = buf[threadIdx.x] - s + partials[blockIdx.x];
#pragma unroll
    for (int t = 0; t < 4; ++t) {
        if (i0 + t < n) { rp[i0 + t] = excl; next[i0 + t] = excl; }
        excl += v[t];
    }
    if (blockIdx.x == 0 && threadIdx.x == 0) rp[n] = total;
}

// CSR SpMM, bf16 gather payload, fp32 accumulate, fused epilogue.
// acc = (Yinit? Yinit[row] : 0) + sum val * bf16(X[col]);
// cur[row] += acc; osum[row] += w*acc; if (outb) outb[row] = bf16(acc).
__global__ __launch_bounds__(256) void spmm_csr_bf16(
    const int* __restrict__ row_ptr, const int2* __restrict__ cv,
    const unsigned short* __restrict__ Xb, const float* __restrict__ Yinit,
    float* __restrict__ cur, float* __restrict__ osum, unsigned short* __restrict__ outb,
    float w, int nrows) {
    int row = (blockIdx.x * 256 + threadIdx.x) >> 5;
    int lane = threadIdx.x & 31;
    if (row >= nrows) return;
    int j = row_ptr[row];
    int end = row_ptr[row + 1];
    size_t off = (size_t)row * D + lane * 4;

    float4 acc = {0, 0, 0, 0};
    if (Yinit) acc = *(const float4*)&Yinit[off];

    for (; j + 4 <= end; j += 4) {
        int2 a = nt_int2(&cv[j]);
        int2 b = nt_int2(&cv[j + 1]);
        int2 cc = nt_int2(&cv[j + 2]);
        int2 dd = nt_int2(&cv[j + 3]);
        ushort4 xa = *(const ushort4*)&Xb[(size_t)a.x * D + lane * 4];
        ushort4 xb = *(const ushort4*)&Xb[(size_t)b.x * D + lane * 4];
        ushort4 xc = *(const ushort4*)&Xb[(size_t)cc.x * D + lane * 4];
        ushort4 xd = *(const ushort4*)&Xb[(size_t)dd.x * D + lane * 4];
        float va = __int_as_float(a.y), vb = __int_as_float(b.y);
        float vc = __int_as_float(cc.y), vd = __int_as_float(dd.y);
        acc.x += va * bf2f(xa.x) + vb * bf2f(xb.x) + vc * bf2f(xc.x) + vd * bf2f(xd.x);
        acc.y += va * bf2f(xa.y) + vb * bf2f(xb.y) + vc * bf2f(xc.y) + vd * bf2f(xd.y);
        acc.z += va * bf2f(xa.z) + vb * bf2f(xb.z) + vc * bf2f(xc.z) + vd * bf2f(xd.z);
        acc.w += va * bf2f(xa.w) + vb * bf2f(xb.w) + vc * bf2f(xc.w) + vd * bf2f(xd.w);
    }
    for (; j < end; ++j) {
        int2 a = nt_int2(&cv[j]);
        float va = __int_as_float(a.y);
        ushort4 xa = *(const ushort4*)&Xb[(size_t)a.x * D + lane * 4];
        acc.x += va * bf2f(xa.x); acc.y += va * bf2f(xa.y);
        acc.z += va * bf2f(xa.z); acc.w += va * bf2f(xa.w);
    }

    float4 c4 = *(const float4*)&cur[off];
    c4.x += acc.x; c4.y += acc.y; c4.z += acc.z; c4.w += acc.w;
    *(float4*)&cur[off] = c4;
    float4 o4 = *(const float4*)&osum[off];
    o4.x += w * acc.x; o4.y += w * acc.y; o4.z += w * acc.z; o4.w += w * acc.w;
    *(float4*)&osum[off] = o4;
    if (outb) {
        ushort4 u;
        u.x = f2bf(acc.x); u.y = f2bf(acc.y); u.z = f2bf(acc.z); u.w = f2bf(acc.w);
        *(ushort4*)&outb[off] = u;
    }
}

extern "C" void kernel_launch(void* const* d_in, const int* in_sizes, int n_in,
                              void* d_out, int out_size, void* d_ws, size_t ws_size,
                              hipStream_t stream) {
    const float* poi   = (const float*)d_in[0];
    const float* edge  = (const float*)d_in[1];
    const float* Wpoi  = (const float*)d_in[2];
    const float* Wedge = (const float*)d_in[3];
    const float* Wfus  = (const float*)d_in[4];
    const int*   p2e_row = (const int*)d_in[5];
    const int*   p2e_col = (const int*)d_in[6];
    const float* p2e_val = (const float*)d_in[7];
    const int*   e2p_row = (const int*)d_in[8];
    const int*   e2p_col = (const int*)d_in[9];
    const float* e2p_val = (const float*)d_in[10];

    float* out_poi  = (float*)d_out;
    float* out_edge = out_poi + (size_t)N_POI * D;

    char* w = (char*)d_ws;
    unsigned short* Ab = (unsigned short*)w; w += (size_t)N_POI * D * 2;   // bf16(p@Wd^T)
    float* B           = (float*)w;          w += (size_t)N_EDGE * D * 4;  // e@Wc^T (spmm1 init)
    unsigned short* Bb = (unsigned short*)w; w += (size_t)N_EDGE * D * 2;  // bf16(fused)
    float* p_cur       = (float*)w;          w += (size_t)N_POI * D * 4;
    float* e_cur       = (float*)w;          w += (size_t)N_EDGE * D * 4;
    float* WdT         = (float*)w;          w += D * D * 4;
    float* WcT         = (float*)w;          w += D * D * 4;
    int*   rp_p2e      = (int*)w;            w += ((N_EDGE + 1) * 4 + 15) / 16 * 16;
    int*   nx_p2e      = (int*)w;            w += (N_EDGE * 4 + 15) / 16 * 16;
    int*   rp_e2p      = (int*)w;            w += ((N_POI + 1) * 4 + 15) / 16 * 16;
    int*   nx_e2p      = (int*)w;            w += (N_POI * 4 + 15) / 16 * 16;
    int*   part0       = (int*)w;            w += 128 * 4;
    int*   part1       = (int*)w;            w += 128 * 4;
    int2*  cv_p2e      = (int2*)w;           w += (size_t)NNZ * 8;
    int2*  cv_e2p      = (int2*)w;           w += (size_t)NNZ * 8;

    // Partial-histogram buffers alias Ab / B: both are only written inside the
    // layer loop, after the CSR build is complete.
    int* part_p2e = (int*)Ab;  // needs C_CH*N_EDGE*4 = 12.8MB <= 25.6MB (Ab)
    int* part_e2p = (int*)B;   // needs C_CH*N_POI *4 = 25.6MB == 25.6MB (B)

    const int NB0 = (N_EDGE + 1023) / 1024;  // 49
    const int NB1 = (N_POI + 1023) / 1024;   // 98

    copy2_kernel<<<2048, 256, 0, stream>>>(poi, p_cur, out_poi, N_POI * D / 4);
    copy2_kernel<<<2048, 256, 0, stream>>>(edge, e_cur, out_edge, N_EDGE * D / 4);
    wcombo_kernel<<<128, 128, 0, stream>>>(Wpoi, Wedge, Wfus, WdT, WcT);

    // ---- CSR build, zero global atomics ----
    // p2e: S=4 shards (logS=2); e2p: S=8 shards (logS=3). Grid = S * C_CH.
    hist_shard<<<4 * C_CH, 256, BPS * 4, stream>>>(p2e_row, part_p2e, 2, N_EDGE);
    hist_shard<<<8 * C_CH, 256, BPS * 4, stream>>>(e2p_row, part_e2p, 3, N_POI);
    reduce_partials<<<(N_EDGE + 255) / 256, 256, 0, stream>>>(part_p2e, nx_p2e, N_EDGE);
    reduce_partials<<<(N_POI + 255) / 256, 256, 0, stream>>>(part_e2p, nx_e2p, N_POI);
    scan_partials<<<NB0, 256, 0, stream>>>(nx_p2e, N_EDGE, part0);
    scan_partials<<<NB1, 256, 0, stream>>>(nx_e2p, N_POI, part1);
    scan_top<<<1, 128, 0, stream>>>(part0, NB0);
    scan_top<<<1, 128, 0, stream>>>(part1, NB1);
    scan_apply<<<NB0, 256, 0, stream>>>(nx_p2e, N_EDGE, part0, rp_p2e, nx_p2e, NNZ);
    scan_apply<<<NB1, 256, 0, stream>>>(nx_e2p, N_POI, part1, rp_e2p, nx_e2p, NNZ);
    prefix_chunks<<<(N_EDGE + 255) / 256, 256, 0, stream>>>(part_p2e, rp_p2e, N_EDGE);
    prefix_chunks<<<(N_POI + 255) / 256, 256, 0, stream>>>(part_e2p, rp_e2p, N_POI);
    scatter_lds<<<4 * C_CH, 256, BPS * 4, stream>>>(p2e_row, p2e_col, p2e_val, part_p2e,
                                                    cv_p2e, 2, N_EDGE);
    scatter_lds<<<8 * C_CH, 256, BPS * 4, stream>>>(e2p_row, e2p_col, e2p_val, part_e2p,
                                                    cv_e2p, 3, N_POI);

    for (int l = 0; l < 2; ++l) {
        float wgt = (l == 0) ? (2.f / 3.f) : (1.f / 3.f);
        dense_xmT<true><<<512, 256, 0, stream>>>(p_cur, WdT, Ab, N_POI);
        dense_xmT<false><<<512, 256, 0, stream>>>(e_cur, WcT, B, N_EDGE);
        // fused = B + spmm(p2e, Ab); e_cur += fused; out_edge += w*fused; Bb = bf16(fused)
        spmm_csr_bf16<<<(N_EDGE + 7) / 8, 256, 0, stream>>>(
            rp_p2e, cv_p2e, Ab, B, e_cur, out_edge, Bb, wgt, N_EDGE);
        // prop = spmm(e2p, Bb); p_cur += prop; out_poi += w*prop
        spmm_csr_bf16<<<(N_POI + 7) / 8, 256, 0, stream>>>(
            rp_e2p, cv_e2p, Bb, nullptr, p_cur, out_poi, nullptr, wgt, N_POI);
    }
}

// Round 2
// 1220.242 us; speedup vs baseline: 1.2667x; 1.0845x over previous
//
#include <hip/hip_runtime.h>

#define N_POI 100000
#define N_EDGE 50000
#define NNZ 3200000
#define D 128

// CSR build tiling: NNZ split into C_CH chunks; bin space sharded BPS bins/shard.
// p2e: 4 shards * 12500 = 50000 bins; e2p: 8 shards * 12500 = 100000 bins.
// 12500 ints = 50KB LDS -> 3 blocks/CU.
#define C_CH 64
#define BPS 12500

__device__ inline unsigned short f2bf(float f) {  // RN-even fp32->bf16
    unsigned int u = __float_as_uint(f);
    return (unsigned short)((u + 0x7fff + ((u >> 16) & 1)) >> 16);
}
__device__ inline float bf2f(unsigned short u) {
    return __uint_as_float(((unsigned int)u) << 16);
}
__device__ inline int2 nt_int2(const int2* p) {
    unsigned long long u = __builtin_nontemporal_load((const unsigned long long*)p);
    int2 r; r.x = (int)(unsigned)(u & 0xffffffffull); r.y = (int)(unsigned)(u >> 32);
    return r;
}

// WdT[j][i] = (Wf1 @ Wpoi)[i][j],  WcT[j][i] = (Wf2 @ Wedge)[i][j]
__global__ __launch_bounds__(128) void wcombo_kernel(const float* __restrict__ Wpoi,
                                                     const float* __restrict__ Wedge,
                                                     const float* __restrict__ Wfus,
                                                     float* __restrict__ WdT,
                                                     float* __restrict__ WcT) {
    int i = blockIdx.x;
    int j = threadIdx.x;
    float s1 = 0.f, s2 = 0.f;
    for (int k = 0; k < D; ++k) {
        float f1 = Wfus[i * 256 + k];
        float f2 = Wfus[i * 256 + 128 + k];
        s1 += f1 * Wpoi[k * D + j];
        s2 += f2 * Wedge[k * D + j];
    }
    WdT[j * D + i] = s1;
    WcT[j * D + i] = s2;
}

// Y[r][c] = sum_k X[r][k] * MT[k][c].  BF16OUT: Y is bf16 (ushort), else fp32.
template <bool BF16OUT>
__global__ __launch_bounds__(256) void dense_xmT(const float* __restrict__ X,
                                                 const float* __restrict__ MT,
                                                 void* __restrict__ Yv, int nrows) {
    __shared__ float mt[D * D];
    __shared__ float xs[32 * D];
    for (int i = threadIdx.x; i < D * D / 4; i += 256)
        ((float4*)mt)[i] = ((const float4*)MT)[i];

    int ntiles = (nrows + 31) >> 5;
    int rg = threadIdx.x >> 5;
    int cg = threadIdx.x & 31;
    int r0 = rg * 4;
    int c0 = cg * 4;

    for (int tile = blockIdx.x; tile < ntiles; tile += gridDim.x) {
        int rbase = tile * 32;
        int nr = min(32, nrows - rbase);
        __syncthreads();
        for (int i = threadIdx.x; i < nr * 32; i += 256)
            ((float4*)xs)[i] = ((const float4*)(X + (size_t)rbase * D))[i];
        __syncthreads();

        float4 a0 = {0, 0, 0, 0}, a1 = {0, 0, 0, 0}, a2 = {0, 0, 0, 0}, a3 = {0, 0, 0, 0};
#pragma unroll 4
        for (int k = 0; k < D; ++k) {
            float4 m = *(const float4*)&mt[k * D + c0];
            float x0 = xs[(r0 + 0) * D + k];
            float x1 = xs[(r0 + 1) * D + k];
            float x2 = xs[(r0 + 2) * D + k];
            float x3 = xs[(r0 + 3) * D + k];
            a0.x += x0 * m.x; a0.y += x0 * m.y; a0.z += x0 * m.z; a0.w += x0 * m.w;
            a1.x += x1 * m.x; a1.y += x1 * m.y; a1.z += x1 * m.z; a1.w += x1 * m.w;
            a2.x += x2 * m.x; a2.y += x2 * m.y; a2.z += x2 * m.z; a2.w += x2 * m.w;
            a3.x += x3 * m.x; a3.y += x3 * m.y; a3.z += x3 * m.z; a3.w += x3 * m.w;
        }
        float4 accs[4] = {a0, a1, a2, a3};
#pragma unroll
        for (int t = 0; t < 4; ++t) {
            if (r0 + t < nr) {
                size_t off = (size_t)(rbase + r0 + t) * D + c0;
                if (BF16OUT) {
                    ushort4 u;
                    u.x = f2bf(accs[t].x); u.y = f2bf(accs[t].y);
                    u.z = f2bf(accs[t].z); u.w = f2bf(accs[t].w);
                    *(ushort4*)&((unsigned short*)Yv)[off] = u;
                } else {
                    *(float4*)&((float*)Yv)[off] = accs[t];
                }
            }
        }
    }
}

// ---- atomic-free CSR build ----
__global__ __launch_bounds__(256) void hist_shard(const int* __restrict__ r,
                                                  int* __restrict__ partial,
                                                  int logS, int nb) {
    extern __shared__ int h[];
    int shard = blockIdx.x & ((1 << logS) - 1);
    int c = blockIdx.x >> logS;
    int lo = shard * BPS;
    for (int i = threadIdx.x; i < BPS; i += 256) h[i] = 0;
    __syncthreads();
    const int chunk4 = (NNZ / C_CH) >> 2;  // 12500 int4 per chunk
    const int4* r4 = (const int4*)r + (size_t)c * chunk4;
    for (int k = threadIdx.x; k < chunk4; k += 256) {
        int4 rr = r4[k];
        unsigned b0 = (unsigned)(rr.x - lo);
        unsigned b1 = (unsigned)(rr.y - lo);
        unsigned b2 = (unsigned)(rr.z - lo);
        unsigned b3 = (unsigned)(rr.w - lo);
        if (b0 < (unsigned)BPS) atomicAdd(&h[b0], 1);
        if (b1 < (unsigned)BPS) atomicAdd(&h[b1], 1);
        if (b2 < (unsigned)BPS) atomicAdd(&h[b2], 1);
        if (b3 < (unsigned)BPS) atomicAdd(&h[b3], 1);
    }
    __syncthreads();
    int* dst = partial + (size_t)c * nb + lo;
    for (int i = threadIdx.x; i < BPS; i += 256) dst[i] = h[i];
}

__global__ __launch_bounds__(256) void reduce_partials(const int* __restrict__ partial,
                                                       int* __restrict__ counts, int nb) {
    int bin = blockIdx.x * 256 + threadIdx.x;
    if (bin >= nb) return;
    int s = 0;
#pragma unroll 8
    for (int c = 0; c < C_CH; ++c) s += partial[(size_t)c * nb + bin];
    counts[bin] = s;
}

__global__ __launch_bounds__(256) void prefix_chunks(int* __restrict__ partial,
                                                     const int* __restrict__ rp, int nb) {
    int bin = blockIdx.x * 256 + threadIdx.x;
    if (bin >= nb) return;
    int run = rp[bin];
    for (int c = 0; c < C_CH; ++c) {
        size_t idx = (size_t)c * nb + bin;
        int v = partial[idx];
        partial[idx] = run;
        run += v;
    }
}

__global__ __launch_bounds__(256) void scatter_lds(const int* __restrict__ r,
                                                   const int* __restrict__ cidx,
                                                   const float* __restrict__ val,
                                                   const int* __restrict__ offs,
                                                   int2* __restrict__ cv,
                                                   int logS, int nb) {
    extern __shared__ int cur[];
    int shard = blockIdx.x & ((1 << logS) - 1);
    int c = blockIdx.x >> logS;
    int lo = shard * BPS;
    const int* src = offs + (size_t)c * nb + lo;
    for (int i = threadIdx.x; i < BPS; i += 256) cur[i] = src[i];
    __syncthreads();
    const int chunk4 = (NNZ / C_CH) >> 2;
    size_t base4 = (size_t)c * chunk4;
    const int4* r4 = (const int4*)r + base4;
    const int4* c4 = (const int4*)cidx + base4;
    const float4* v4 = (const float4*)val + base4;
    for (int k = threadIdx.x; k < chunk4; k += 256) {
        int4 rr = r4[k];
        int4 cc = c4[k];
        float4 vv = v4[k];
        unsigned b0 = (unsigned)(rr.x - lo);
        if (b0 < (unsigned)BPS) { int p = atomicAdd(&cur[b0], 1); cv[p] = make_int2(cc.x, __float_as_int(vv.x)); }
        unsigned b1 = (unsigned)(rr.y - lo);
        if (b1 < (unsigned)BPS) { int p = atomicAdd(&cur[b1], 1); cv[p] = make_int2(cc.y, __float_as_int(vv.y)); }
        unsigned b2 = (unsigned)(rr.z - lo);
        if (b2 < (unsigned)BPS) { int p = atomicAdd(&cur[b2], 1); cv[p] = make_int2(cc.z, __float_as_int(vv.z)); }
        unsigned b3 = (unsigned)(rr.w - lo);
        if (b3 < (unsigned)BPS) { int p = atomicAdd(&cur[b3], 1); cv[p] = make_int2(cc.w, __float_as_int(vv.w)); }
    }
}

// ---- 3-phase multi-block exclusive scan (1024 elems/block) ----
__global__ __launch_bounds__(256) void scan_partials(const int* __restrict__ counts, int n,
                                                     int* __restrict__ partials) {
    __shared__ int red[256];
    int i0 = blockIdx.x * 1024 + threadIdx.x * 4;
    int s = 0;
#pragma unroll
    for (int t = 0; t < 4; ++t)
        if (i0 + t < n) s += counts[i0 + t];
    red[threadIdx.x] = s;
    __syncthreads();
    for (int off = 128; off > 0; off >>= 1) {
        if (threadIdx.x < off) red[threadIdx.x] += red[threadIdx.x + off];
        __syncthreads();
    }
    if (threadIdx.x == 0) partials[blockIdx.x] = red[0];
}

__global__ __launch_bounds__(128) void scan_top(int* partials, int nb) {
    __shared__ int buf[128];
    int v = (threadIdx.x < nb) ? partials[threadIdx.x] : 0;
    buf[threadIdx.x] = v;
    __syncthreads();
    for (int off = 1; off < 128; off <<= 1) {
        int t = (threadIdx.x >= off) ? buf[threadIdx.x - off] : 0;
        __syncthreads();
        buf[threadIdx.x] += t;
        __syncthreads();
    }
    if (threadIdx.x < nb) partials[threadIdx.x] = buf[threadIdx.x] - v;
}

__global__ __launch_bounds__(256) void scan_apply(const int* __restrict__ counts, int n,
                                                  const int* __restrict__ partials,
                                                  int* __restrict__ rp, int* __restrict__ next,
                                                  int total) {
    __shared__ int buf[256];
    int i0 = blockIdx.x * 1024 + threadIdx.x * 4;
    int v[4];
#pragma unroll
    for (int t = 0; t < 4; ++t) v[t] = (i0 + t < n) ? counts[i0 + t] : 0;
    int s = v[0] + v[1] + v[2] + v[3];
    buf[threadIdx.x] = s;
    __syncthreads();
    for (int off = 1; off < 256; off <<= 1) {
        int t = (threadIdx.x >= off) ? buf[threadIdx.x - off] : 0;
        __syncthreads();
        buf[threadIdx.x] += t;
        __syncthreads();
    }
    int excl = buf[threadIdx.x] - s + partials[blockIdx.x];
#pragma unroll
    for (int t = 0; t < 4; ++t) {
        if (i0 + t < n) { rp[i0 + t] = excl; next[i0 + t] = excl; }
        excl += v[t];
    }
    if (blockIdx.x == 0 && threadIdx.x == 0) rp[n] = total;
}

// CSR SpMM with algebraic epilogue (no RMW accumulators, no osum):
//   t = (HAS_Y ? Yinit[row] : 0) + sum val * bf16(X[col])
//   outF[row] = c0*base0[row] + (HAS_B1 ? c1*base1[row] : 0) + c2*t
//   if (HAS_OB) outb[row] = bf16(t)
template <bool HAS_Y, bool HAS_B1, bool HAS_OB>
__global__ __launch_bounds__(256) void spmm_csr_fused(
    const int* __restrict__ row_ptr, const int2* __restrict__ cv,
    const unsigned short* __restrict__ Xb, const float* __restrict__ Yinit,
    const float* __restrict__ base0, const float* __restrict__ base1,
    float* __restrict__ outF, unsigned short* __restrict__ outb,
    float c0, float c1, float c2, int nrows) {
    int row = (blockIdx.x * 256 + threadIdx.x) >> 5;
    int lane = threadIdx.x & 31;
    if (row >= nrows) return;
    int j = row_ptr[row];
    int end = row_ptr[row + 1];
    size_t off = (size_t)row * D + lane * 4;

    float4 acc = {0, 0, 0, 0};
    if (HAS_Y) acc = *(const float4*)&Yinit[off];

    // 8-deep gather pipeline: 8 cv loads, then 8 independent 8B table gathers.
    for (; j + 8 <= end; j += 8) {
        int2 e[8];
#pragma unroll
        for (int t = 0; t < 8; ++t) e[t] = nt_int2(&cv[j + t]);
        ushort4 x[8];
#pragma unroll
        for (int t = 0; t < 8; ++t)
            x[t] = *(const ushort4*)&Xb[(size_t)e[t].x * D + lane * 4];
#pragma unroll
        for (int t = 0; t < 8; ++t) {
            float v = __int_as_float(e[t].y);
            acc.x += v * bf2f(x[t].x); acc.y += v * bf2f(x[t].y);
            acc.z += v * bf2f(x[t].z); acc.w += v * bf2f(x[t].w);
        }
    }
    for (; j < end; ++j) {
        int2 a = nt_int2(&cv[j]);
        float va = __int_as_float(a.y);
        ushort4 xa = *(const ushort4*)&Xb[(size_t)a.x * D + lane * 4];
        acc.x += va * bf2f(xa.x); acc.y += va * bf2f(xa.y);
        acc.z += va * bf2f(xa.z); acc.w += va * bf2f(xa.w);
    }

    float4 b0 = *(const float4*)&base0[off];
    float4 o;
    o.x = c0 * b0.x + c2 * acc.x;
    o.y = c0 * b0.y + c2 * acc.y;
    o.z = c0 * b0.z + c2 * acc.z;
    o.w = c0 * b0.w + c2 * acc.w;
    if (HAS_B1) {
        float4 b1 = *(const float4*)&base1[off];
        o.x += c1 * b1.x; o.y += c1 * b1.y; o.z += c1 * b1.z; o.w += c1 * b1.w;
    }
    *(float4*)&outF[off] = o;
    if (HAS_OB) {
        ushort4 u;
        u.x = f2bf(acc.x); u.y = f2bf(acc.y); u.z = f2bf(acc.z); u.w = f2bf(acc.w);
        *(ushort4*)&outb[off] = u;
    }
}

extern "C" void kernel_launch(void* const* d_in, const int* in_sizes, int n_in,
                              void* d_out, int out_size, void* d_ws, size_t ws_size,
                              hipStream_t stream) {
    const float* poi   = (const float*)d_in[0];
    const float* edge  = (const float*)d_in[1];
    const float* Wpoi  = (const float*)d_in[2];
    const float* Wedge = (const float*)d_in[3];
    const float* Wfus  = (const float*)d_in[4];
    const int*   p2e_row = (const int*)d_in[5];
    const int*   p2e_col = (const int*)d_in[6];
    const float* p2e_val = (const float*)d_in[7];
    const int*   e2p_row = (const int*)d_in[8];
    const int*   e2p_col = (const int*)d_in[9];
    const float* e2p_val = (const float*)d_in[10];

    float* out_poi  = (float*)d_out;
    float* out_edge = out_poi + (size_t)N_POI * D;

    char* w = (char*)d_ws;
    unsigned short* Ab = (unsigned short*)w; w += (size_t)N_POI * D * 2;   // bf16(p@Wd^T)
    float* B           = (float*)w;          w += (size_t)N_EDGE * D * 4;  // e@Wc^T (spmm1 init)
    unsigned short* Bb = (unsigned short*)w; w += (size_t)N_EDGE * D * 2;  // bf16(fused)
    float* p_cur       = (float*)w;          w += (size_t)N_POI * D * 4;   // p after layer 1
    float* e_cur       = (float*)w;          w += (size_t)N_EDGE * D * 4;  // e after layer 1
    float* WdT         = (float*)w;          w += D * D * 4;
    float* WcT         = (float*)w;          w += D * D * 4;
    int*   rp_p2e      = (int*)w;            w += ((N_EDGE + 1) * 4 + 15) / 16 * 16;
    int*   nx_p2e      = (int*)w;            w += (N_EDGE * 4 + 15) / 16 * 16;
    int*   rp_e2p      = (int*)w;            w += ((N_POI + 1) * 4 + 15) / 16 * 16;
    int*   nx_e2p      = (int*)w;            w += (N_POI * 4 + 15) / 16 * 16;
    int*   part0       = (int*)w;            w += 128 * 4;
    int*   part1       = (int*)w;            w += 128 * 4;
    int2*  cv_p2e      = (int2*)w;           w += (size_t)NNZ * 8;
    int2*  cv_e2p      = (int2*)w;           w += (size_t)NNZ * 8;

    // Partial-histogram buffers alias Ab / B: both are only written inside the
    // layer loop, after the CSR build is complete.
    int* part_p2e = (int*)Ab;  // needs C_CH*N_EDGE*4 = 12.8MB <= 25.6MB (Ab)
    int* part_e2p = (int*)B;   // needs C_CH*N_POI *4 = 25.6MB == 25.6MB (B)

    const int NB0 = (N_EDGE + 1023) / 1024;  // 49
    const int NB1 = (N_POI + 1023) / 1024;   // 98

    wcombo_kernel<<<128, 128, 0, stream>>>(Wpoi, Wedge, Wfus, WdT, WcT);

    // ---- CSR build, zero global atomics ----
    hist_shard<<<4 * C_CH, 256, BPS * 4, stream>>>(p2e_row, part_p2e, 2, N_EDGE);
    hist_shard<<<8 * C_CH, 256, BPS * 4, stream>>>(e2p_row, part_e2p, 3, N_POI);
    reduce_partials<<<(N_EDGE + 255) / 256, 256, 0, stream>>>(part_p2e, nx_p2e, N_EDGE);
    reduce_partials<<<(N_POI + 255) / 256, 256, 0, stream>>>(part_e2p, nx_e2p, N_POI);
    scan_partials<<<NB0, 256, 0, stream>>>(nx_p2e, N_EDGE, part0);
    scan_partials<<<NB1, 256, 0, stream>>>(nx_e2p, N_POI, part1);
    scan_top<<<1, 128, 0, stream>>>(part0, NB0);
    scan_top<<<1, 128, 0, stream>>>(part1, NB1);
    scan_apply<<<NB0, 256, 0, stream>>>(nx_p2e, N_EDGE, part0, rp_p2e, nx_p2e, NNZ);
    scan_apply<<<NB1, 256, 0, stream>>>(nx_e2p, N_POI, part1, rp_e2p, nx_e2p, NNZ);
    prefix_chunks<<<(N_EDGE + 255) / 256, 256, 0, stream>>>(part_p2e, rp_p2e, N_EDGE);
    prefix_chunks<<<(N_POI + 255) / 256, 256, 0, stream>>>(part_e2p, rp_e2p, N_POI);
    scatter_lds<<<4 * C_CH, 256, BPS * 4, stream>>>(p2e_row, p2e_col, p2e_val, part_p2e,
                                                    cv_p2e, 2, N_EDGE);
    scatter_lds<<<8 * C_CH, 256, BPS * 4, stream>>>(e2p_row, e2p_col, e2p_val, part_e2p,
                                                    cv_e2p, 3, N_POI);

    const float T = 1.f / 3.f;

    // ---- layer 0 ----
    dense_xmT<true><<<512, 256, 0, stream>>>(poi, WdT, Ab, N_POI);     // Ab = bf16(p0@Wd^T)
    dense_xmT<false><<<512, 256, 0, stream>>>(edge, WcT, B, N_EDGE);   // B = e0@Wc^T
    // fused1 = B + spmm(p2e, Ab); e_cur = edge + fused1; Bb = bf16(fused1)
    spmm_csr_fused<true, false, true><<<(N_EDGE + 7) / 8, 256, 0, stream>>>(
        rp_p2e, cv_p2e, Ab, B, edge, nullptr, e_cur, Bb, 1.f, 0.f, 1.f, N_EDGE);
    // prop1 = spmm(e2p, Bb); p_cur = poi + prop1
    spmm_csr_fused<false, false, false><<<(N_POI + 7) / 8, 256, 0, stream>>>(
        rp_e2p, cv_e2p, Bb, nullptr, poi, nullptr, p_cur, nullptr, 1.f, 0.f, 1.f, N_POI);

    // ---- layer 1 (writes final outputs directly) ----
    dense_xmT<true><<<512, 256, 0, stream>>>(p_cur, WdT, Ab, N_POI);
    dense_xmT<false><<<512, 256, 0, stream>>>(e_cur, WcT, B, N_EDGE);
    // fused2 = B + spmm(p2e, Ab); out_edge = (edge + 2*e_cur + fused2)/3; Bb = bf16(fused2)
    spmm_csr_fused<true, true, true><<<(N_EDGE + 7) / 8, 256, 0, stream>>>(
        rp_p2e, cv_p2e, Ab, B, edge, e_cur, out_edge, Bb, T, 2.f * T, T, N_EDGE);
    // prop2 = spmm(e2p, Bb); out_poi = (poi + 2*p_cur + prop2)/3
    spmm_csr_fused<false, true, false><<<(N_POI + 7) / 8, 256, 0, stream>>>(
        rp_e2p, cv_e2p, Bb, nullptr, poi, p_cur, out_poi, nullptr, T, 2.f * T, T, N_POI);
}

// Round 4
// 1060.290 us; speedup vs baseline: 1.4577x; 1.1509x over previous
//
#include <hip/hip_runtime.h>

#define N_POI 100000
#define N_EDGE 50000
#define NNZ 3200000
#define D 128

// 2-pass bucket radix sort for CSR build.
// Buckets: row>>SH, NBKT=196 for both matrices (e2p: 100000>>9, p2e: 50000>>8).
// Pass 1: tile-local LDS sort by bucket + coalesced run writeout.
// Pass 2: per-bucket block: LDS row-hist -> row_ptr, then scatter within the
//         bucket's ~130KB cv region (L2-resident -> full-line writebacks).
#define NBKT 196
#define SH_P2E 8
#define SH_E2P 9
#define PTILE 4000
#define PGRID 800  // NNZ / PTILE exactly

__device__ inline unsigned short f2bf(float f) {  // RN-even fp32->bf16
    unsigned int u = __float_as_uint(f);
    return (unsigned short)((u + 0x7fff + ((u >> 16) & 1)) >> 16);
}
__device__ inline float bf2f(unsigned short u) {
    return __uint_as_float(((unsigned int)u) << 16);
}
__device__ inline int2 nt_int2(const int2* p) {
    unsigned long long u = __builtin_nontemporal_load((const unsigned long long*)p);
    int2 r; r.x = (int)(unsigned)(u & 0xffffffffull); r.y = (int)(unsigned)(u >> 32);
    return r;
}

// WdT[j][i] = (Wf1 @ Wpoi)[i][j],  WcT[j][i] = (Wf2 @ Wedge)[i][j]
__global__ __launch_bounds__(128) void wcombo_kernel(const float* __restrict__ Wpoi,
                                                     const float* __restrict__ Wedge,
                                                     const float* __restrict__ Wfus,
                                                     float* __restrict__ WdT,
                                                     float* __restrict__ WcT) {
    int i = blockIdx.x;
    int j = threadIdx.x;
    float s1 = 0.f, s2 = 0.f;
    for (int k = 0; k < D; ++k) {
        float f1 = Wfus[i * 256 + k];
        float f2 = Wfus[i * 256 + 128 + k];
        s1 += f1 * Wpoi[k * D + j];
        s2 += f2 * Wedge[k * D + j];
    }
    WdT[j * D + i] = s1;
    WcT[j * D + i] = s2;
}

// Y[r][c] = sum_k X[r][k] * MT[k][c].  BF16OUT: Y is bf16 (ushort), else fp32.
template <bool BF16OUT>
__global__ __launch_bounds__(256) void dense_xmT(const float* __restrict__ X,
                                                 const float* __restrict__ MT,
                                                 void* __restrict__ Yv, int nrows) {
    __shared__ float mt[D * D];
    __shared__ float xs[32 * D];
    for (int i = threadIdx.x; i < D * D / 4; i += 256)
        ((float4*)mt)[i] = ((const float4*)MT)[i];

    int ntiles = (nrows + 31) >> 5;
    int rg = threadIdx.x >> 5;
    int cg = threadIdx.x & 31;
    int r0 = rg * 4;
    int c0 = cg * 4;

    for (int tile = blockIdx.x; tile < ntiles; tile += gridDim.x) {
        int rbase = tile * 32;
        int nr = min(32, nrows - rbase);
        __syncthreads();
        for (int i = threadIdx.x; i < nr * 32; i += 256)
            ((float4*)xs)[i] = ((const float4*)(X + (size_t)rbase * D))[i];
        __syncthreads();

        float4 a0 = {0, 0, 0, 0}, a1 = {0, 0, 0, 0}, a2 = {0, 0, 0, 0}, a3 = {0, 0, 0, 0};
#pragma unroll 4
        for (int k = 0; k < D; ++k) {
            float4 m = *(const float4*)&mt[k * D + c0];
            float x0 = xs[(r0 + 0) * D + k];
            float x1 = xs[(r0 + 1) * D + k];
            float x2 = xs[(r0 + 2) * D + k];
            float x3 = xs[(r0 + 3) * D + k];
            a0.x += x0 * m.x; a0.y += x0 * m.y; a0.z += x0 * m.z; a0.w += x0 * m.w;
            a1.x += x1 * m.x; a1.y += x1 * m.y; a1.z += x1 * m.z; a1.w += x1 * m.w;
            a2.x += x2 * m.x; a2.y += x2 * m.y; a2.z += x2 * m.z; a2.w += x2 * m.w;
            a3.x += x3 * m.x; a3.y += x3 * m.y; a3.z += x3 * m.z; a3.w += x3 * m.w;
        }
        float4 accs[4] = {a0, a1, a2, a3};
#pragma unroll
        for (int t = 0; t < 4; ++t) {
            if (r0 + t < nr) {
                size_t off = (size_t)(rbase + r0 + t) * D + c0;
                if (BF16OUT) {
                    ushort4 u;
                    u.x = f2bf(accs[t].x); u.y = f2bf(accs[t].y);
                    u.z = f2bf(accs[t].z); u.w = f2bf(accs[t].w);
                    *(ushort4*)&((unsigned short*)Yv)[off] = u;
                } else {
                    *(float4*)&((float*)Yv)[off] = accs[t];
                }
            }
        }
    }
}

// ---- CSR build: 2-pass bucket radix sort ----

// Bucket totals (196 coarse bins): LDS hist + one global atomic per (block,bin).
__global__ __launch_bounds__(256) void bkt_count(const int* __restrict__ r, int sh,
                                                 int* __restrict__ tot) {
    __shared__ int h[NBKT];
    for (int i = threadIdx.x; i < NBKT; i += 256) h[i] = 0;
    __syncthreads();
    const int4* r4 = (const int4*)r;
    const int n4 = NNZ / 4;
    for (int k = blockIdx.x * 256 + threadIdx.x; k < n4; k += gridDim.x * 256) {
        int4 rr = r4[k];
        atomicAdd(&h[rr.x >> sh], 1);
        atomicAdd(&h[rr.y >> sh], 1);
        atomicAdd(&h[rr.z >> sh], 1);
        atomicAdd(&h[rr.w >> sh], 1);
    }
    __syncthreads();
    for (int i = threadIdx.x; i < NBKT; i += 256)
        if (h[i]) atomicAdd(&tot[i], h[i]);
}

// Exclusive scan of bucket totals -> base[0..NBKT]; init run cursors; rp[nrows]=NNZ.
__global__ __launch_bounds__(256) void bkt_scan(const int* __restrict__ tot,
                                                int* __restrict__ base,
                                                int* __restrict__ gcur,
                                                int* __restrict__ rp, int nrows) {
    __shared__ int buf[256];
    int v = (threadIdx.x < NBKT) ? tot[threadIdx.x] : 0;
    buf[threadIdx.x] = v;
    __syncthreads();
    for (int off = 1; off < 256; off <<= 1) {
        int t = (threadIdx.x >= off) ? buf[threadIdx.x - off] : 0;
        __syncthreads();
        buf[threadIdx.x] += t;
        __syncthreads();
    }
    int excl = buf[threadIdx.x] - v;
    if (threadIdx.x < NBKT) { base[threadIdx.x] = excl; gcur[threadIdx.x] = excl; }
    if (threadIdx.x == 0) { base[NBKT] = NNZ; rp[nrows] = NNZ; }
}

// Pass 1: tile-local bucket sort in LDS, then coalesced run writeout.
__global__ __launch_bounds__(256) void partition_kernel(
    const int* __restrict__ r, const int* __restrict__ c, const float* __restrict__ v,
    int* __restrict__ gcur, int sh, int* __restrict__ rb, int2* __restrict__ cvb) {
    __shared__ int hist[NBKT];
    __shared__ int excl[NBKT];
    __shared__ int cur[NBKT];
    __shared__ int runb[NBKT];
    __shared__ int sbuf[256];
    __shared__ int rs[PTILE];
    __shared__ int2 cvs[PTILE];
    const int base = blockIdx.x * PTILE;
    for (int i = threadIdx.x; i < NBKT; i += 256) hist[i] = 0;
    __syncthreads();
    const int4* r4 = (const int4*)(r + base);
    for (int k = threadIdx.x; k < PTILE / 4; k += 256) {
        int4 rr = r4[k];
        atomicAdd(&hist[rr.x >> sh], 1);
        atomicAdd(&hist[rr.y >> sh], 1);
        atomicAdd(&hist[rr.z >> sh], 1);
        atomicAdd(&hist[rr.w >> sh], 1);
    }
    __syncthreads();
    int hv = (threadIdx.x < NBKT) ? hist[threadIdx.x] : 0;
    sbuf[threadIdx.x] = hv;
    __syncthreads();
    for (int off = 1; off < 256; off <<= 1) {
        int t = (threadIdx.x >= off) ? sbuf[threadIdx.x - off] : 0;
        __syncthreads();
        sbuf[threadIdx.x] += t;
        __syncthreads();
    }
    if (threadIdx.x < NBKT) {
        int e = sbuf[threadIdx.x] - hv;
        excl[threadIdx.x] = e;
        cur[threadIdx.x] = e;
        runb[threadIdx.x] = hv ? atomicAdd(&gcur[threadIdx.x], hv) : 0;
    }
    __syncthreads();
    const int4* c4 = (const int4*)(c + base);
    const float4* v4 = (const float4*)(v + base);
    for (int k = threadIdx.x; k < PTILE / 4; k += 256) {
        int4 rr = r4[k];
        int4 cc = c4[k];
        float4 vv = v4[k];
        int p;
        p = atomicAdd(&cur[rr.x >> sh], 1); rs[p] = rr.x; cvs[p] = make_int2(cc.x, __float_as_int(vv.x));
        p = atomicAdd(&cur[rr.y >> sh], 1); rs[p] = rr.y; cvs[p] = make_int2(cc.y, __float_as_int(vv.y));
        p = atomicAdd(&cur[rr.z >> sh], 1); rs[p] = rr.z; cvs[p] = make_int2(cc.z, __float_as_int(vv.z));
        p = atomicAdd(&cur[rr.w >> sh], 1); rs[p] = rr.w; cvs[p] = make_int2(cc.w, __float_as_int(vv.w));
    }
    __syncthreads();
    for (int p = threadIdx.x; p < PTILE; p += 256) {
        int row = rs[p];
        int b = row >> sh;
        int dst = runb[b] + (p - excl[b]);
        rb[dst] = row;
        cvb[dst] = cvs[p];
    }
}

// Pass 2: per-bucket block. Sweep 1: row hist -> row_ptr (+cursors);
// sweep 2: scatter cv within the bucket's small region.
__global__ __launch_bounds__(512) void bucket_scatter(
    const int* __restrict__ base, const int* __restrict__ rb, const int2* __restrict__ cvb,
    int sh, int nrows, int* __restrict__ rp, int2* __restrict__ cv) {
    __shared__ int cur[512];
    __shared__ int sbuf[512];
    const int b = blockIdx.x;
    const int s0 = base[b];
    const int n = base[b + 1] - s0;
    const int row0 = b << sh;
    const int nr = min(1 << sh, nrows - row0);
    for (int i = threadIdx.x; i < (1 << sh); i += 512) cur[i] = 0;
    __syncthreads();
    for (int k = threadIdx.x; k < n; k += 512)
        atomicAdd(&cur[rb[s0 + k] - row0], 1);
    __syncthreads();
    int cnt = (threadIdx.x < (1 << sh)) ? cur[threadIdx.x] : 0;
    sbuf[threadIdx.x] = cnt;
    __syncthreads();
    for (int off = 1; off < 512; off <<= 1) {
        int t = (threadIdx.x >= off) ? sbuf[threadIdx.x - off] : 0;
        __syncthreads();
        sbuf[threadIdx.x] += t;
        __syncthreads();
    }
    if (threadIdx.x < (1 << sh)) {
        int e = s0 + sbuf[threadIdx.x] - cnt;
        cur[threadIdx.x] = e;
        if (threadIdx.x < nr) rp[row0 + threadIdx.x] = e;
    }
    __syncthreads();
    for (int k = threadIdx.x; k < n; k += 512) {
        int row = rb[s0 + k];
        int p = atomicAdd(&cur[row - row0], 1);
        cv[p] = cvb[s0 + k];
    }
}

// CSR SpMM with algebraic epilogue (no RMW accumulators):
//   t = (HAS_Y ? Yinit[row] : 0) + sum val * bf16(X[col])
//   outF[row] = c0*base0[row] + (HAS_B1 ? c1*base1[row] : 0) + c2*t
//   if (HAS_OB) outb[row] = bf16(t)
template <bool HAS_Y, bool HAS_B1, bool HAS_OB>
__global__ __launch_bounds__(256) void spmm_csr_fused(
    const int* __restrict__ row_ptr, const int2* __restrict__ cv,
    const unsigned short* __restrict__ Xb, const float* __restrict__ Yinit,
    const float* __restrict__ base0, const float* __restrict__ base1,
    float* __restrict__ outF, unsigned short* __restrict__ outb,
    float c0, float c1, float c2, int nrows) {
    int row = (blockIdx.x * 256 + threadIdx.x) >> 5;
    int lane = threadIdx.x & 31;
    if (row >= nrows) return;
    int j = row_ptr[row];
    int end = row_ptr[row + 1];
    size_t off = (size_t)row * D + lane * 4;

    float4 acc = {0, 0, 0, 0};
    if (HAS_Y) acc = *(const float4*)&Yinit[off];

    for (; j + 8 <= end; j += 8) {
        int2 e[8];
#pragma unroll
        for (int t = 0; t < 8; ++t) e[t] = nt_int2(&cv[j + t]);
        ushort4 x[8];
#pragma unroll
        for (int t = 0; t < 8; ++t)
            x[t] = *(const ushort4*)&Xb[(size_t)e[t].x * D + lane * 4];
#pragma unroll
        for (int t = 0; t < 8; ++t) {
            float v = __int_as_float(e[t].y);
            acc.x += v * bf2f(x[t].x); acc.y += v * bf2f(x[t].y);
            acc.z += v * bf2f(x[t].z); acc.w += v * bf2f(x[t].w);
        }
    }
    for (; j < end; ++j) {
        int2 a = nt_int2(&cv[j]);
        float va = __int_as_float(a.y);
        ushort4 xa = *(const ushort4*)&Xb[(size_t)a.x * D + lane * 4];
        acc.x += va * bf2f(xa.x); acc.y += va * bf2f(xa.y);
        acc.z += va * bf2f(xa.z); acc.w += va * bf2f(xa.w);
    }

    float4 b0 = *(const float4*)&base0[off];
    float4 o;
    o.x = c0 * b0.x + c2 * acc.x;
    o.y = c0 * b0.y + c2 * acc.y;
    o.z = c0 * b0.z + c2 * acc.z;
    o.w = c0 * b0.w + c2 * acc.w;
    if (HAS_B1) {
        float4 b1 = *(const float4*)&base1[off];
        o.x += c1 * b1.x; o.y += c1 * b1.y; o.z += c1 * b1.z; o.w += c1 * b1.w;
    }
    *(float4*)&outF[off] = o;
    if (HAS_OB) {
        ushort4 u;
        u.x = f2bf(acc.x); u.y = f2bf(acc.y); u.z = f2bf(acc.z); u.w = f2bf(acc.w);
        *(ushort4*)&outb[off] = u;
    }
}

extern "C" void kernel_launch(void* const* d_in, const int* in_sizes, int n_in,
                              void* d_out, int out_size, void* d_ws, size_t ws_size,
                              hipStream_t stream) {
    const float* poi   = (const float*)d_in[0];
    const float* edge  = (const float*)d_in[1];
    const float* Wpoi  = (const float*)d_in[2];
    const float* Wedge = (const float*)d_in[3];
    const float* Wfus  = (const float*)d_in[4];
    const int*   p2e_row = (const int*)d_in[5];
    const int*   p2e_col = (const int*)d_in[6];
    const float* p2e_val = (const float*)d_in[7];
    const int*   e2p_row = (const int*)d_in[8];
    const int*   e2p_col = (const int*)d_in[9];
    const float* e2p_val = (const float*)d_in[10];

    float* out_poi  = (float*)d_out;
    float* out_edge = out_poi + (size_t)N_POI * D;

    char* w = (char*)d_ws;
    unsigned short* Ab = (unsigned short*)w; w += (size_t)N_POI * D * 2;   // bf16(p@Wd^T)
    float* B           = (float*)w;          w += (size_t)N_EDGE * D * 4;  // e@Wc^T (spmm1 init)
    unsigned short* Bb = (unsigned short*)w; w += (size_t)N_EDGE * D * 2;  // bf16(fused)
    float* p_cur       = (float*)w;          w += (size_t)N_POI * D * 4;   // p after layer 1
    float* e_cur       = (float*)w;          w += (size_t)N_EDGE * D * 4;  // e after layer 1
    float* WdT         = (float*)w;          w += D * D * 4;
    float* WcT         = (float*)w;          w += D * D * 4;
    int*   rp_p2e      = (int*)w;            w += ((N_EDGE + 1) * 4 + 15) / 16 * 16;
    int*   rp_e2p      = (int*)w;            w += ((N_POI + 1) * 4 + 15) / 16 * 16;
    int*   bkt_tot     = (int*)w;            w += 256 * 4;
    int*   bkt_base    = (int*)w;            w += 256 * 4;
    int*   bkt_cur     = (int*)w;            w += 256 * 4;
    int2*  cv_p2e      = (int2*)w;           w += (size_t)NNZ * 8;
    int2*  cv_e2p      = (int2*)w;           w += (size_t)NNZ * 8;

    // Staging buffers for the sort alias Ab/B (both only written inside the
    // layer loop, which runs after the builds complete).
    int*  rb_g  = (int*)Ab;   // NNZ*4 = 12.8MB <= 25.6MB (Ab)
    int2* cvb_g = (int2*)B;   // NNZ*8 = 25.6MB == 25.6MB (B)

    wcombo_kernel<<<128, 128, 0, stream>>>(Wpoi, Wedge, Wfus, WdT, WcT);

    // ---- p2e build ----
    hipMemsetAsync(bkt_tot, 0, NBKT * sizeof(int), stream);
    bkt_count<<<256, 256, 0, stream>>>(p2e_row, SH_P2E, bkt_tot);
    bkt_scan<<<1, 256, 0, stream>>>(bkt_tot, bkt_base, bkt_cur, rp_p2e, N_EDGE);
    partition_kernel<<<PGRID, 256, 0, stream>>>(p2e_row, p2e_col, p2e_val, bkt_cur,
                                                SH_P2E, rb_g, cvb_g);
    bucket_scatter<<<NBKT, 512, 0, stream>>>(bkt_base, rb_g, cvb_g, SH_P2E, N_EDGE,
                                             rp_p2e, cv_p2e);

    // ---- e2p build (reuses staging + bucket arrays) ----
    hipMemsetAsync(bkt_tot, 0, NBKT * sizeof(int), stream);
    bkt_count<<<256, 256, 0, stream>>>(e2p_row, SH_E2P, bkt_tot);
    bkt_scan<<<1, 256, 0, stream>>>(bkt_tot, bkt_base, bkt_cur, rp_e2p, N_POI);
    partition_kernel<<<PGRID, 256, 0, stream>>>(e2p_row, e2p_col, e2p_val, bkt_cur,
                                                SH_E2P, rb_g, cvb_g);
    bucket_scatter<<<NBKT, 512, 0, stream>>>(bkt_base, rb_g, cvb_g, SH_E2P, N_POI,
                                             rp_e2p, cv_e2p);

    const float T = 1.f / 3.f;

    // ---- layer 0 ----
    dense_xmT<true><<<512, 256, 0, stream>>>(poi, WdT, Ab, N_POI);     // Ab = bf16(p0@Wd^T)
    dense_xmT<false><<<512, 256, 0, stream>>>(edge, WcT, B, N_EDGE);   // B = e0@Wc^T
    // fused1 = B + spmm(p2e, Ab); e_cur = edge + fused1; Bb = bf16(fused1)
    spmm_csr_fused<true, false, true><<<(N_EDGE + 7) / 8, 256, 0, stream>>>(
        rp_p2e, cv_p2e, Ab, B, edge, nullptr, e_cur, Bb, 1.f, 0.f, 1.f, N_EDGE);
    // prop1 = spmm(e2p, Bb); p_cur = poi + prop1
    spmm_csr_fused<false, false, false><<<(N_POI + 7) / 8, 256, 0, stream>>>(
        rp_e2p, cv_e2p, Bb, nullptr, poi, nullptr, p_cur, nullptr, 1.f, 0.f, 1.f, N_POI);

    // ---- layer 1 (writes final outputs directly) ----
    dense_xmT<true><<<512, 256, 0, stream>>>(p_cur, WdT, Ab, N_POI);
    dense_xmT<false><<<512, 256, 0, stream>>>(e_cur, WcT, B, N_EDGE);
    // fused2 = B + spmm(p2e, Ab); out_edge = (edge + 2*e_cur + fused2)/3; Bb = bf16(fused2)
    spmm_csr_fused<true, true, true><<<(N_EDGE + 7) / 8, 256, 0, stream>>>(
        rp_p2e, cv_p2e, Ab, B, edge, e_cur, out_edge, Bb, T, 2.f * T, T, N_EDGE);
    // prop2 = spmm(e2p, Bb); out_poi = (poi + 2*p_cur + prop2)/3
    spmm_csr_fused<false, true, false><<<(N_POI + 7) / 8, 256, 0, stream>>>(
        rp_e2p, cv_e2p, Bb, nullptr, poi, p_cur, out_poi, nullptr, T, 2.f * T, T, N_POI);
}